// Round 8
// baseline (196.067 us; speedup 1.0000x reference)
//
#include <hip/hip_runtime.h>
#include <math.h>

#define B_  2
#define S_  2048
#define D_  1024
#define H_  16
#define DH_ 64

typedef unsigned short u16;
typedef unsigned int   u32;
typedef _Float16       f16;
typedef _Float16 half8  __attribute__((ext_vector_type(8)));
typedef _Float16 half4  __attribute__((ext_vector_type(4)));
typedef float    f32x4  __attribute__((ext_vector_type(4)));
typedef float    f32x16 __attribute__((ext_vector_type(16)));

#if __has_builtin(__builtin_amdgcn_exp2f)
#define EXP2(x) __builtin_amdgcn_exp2f(x)
#else
#define EXP2(x) exp2f(x)
#endif

__device__ __forceinline__ u16 h_bits(f16 h){ return __builtin_bit_cast(u16, h); }

// split 8 fp32 -> packed hi/lo f16 (bit-identical to the old prep path)
__device__ __forceinline__ void split8(float4 a, float4 b, uint4& H, uint4& L){
    float fv[8] = {a.x, a.y, a.z, a.w, b.x, b.y, b.z, b.w};
    u32 hw[4], lw[4];
    #pragma unroll
    for (int j = 0; j < 4; ++j){
        f16 h0 = (f16)fv[2*j],   h1 = (f16)fv[2*j+1];
        f16 l0 = (f16)(fv[2*j]   - (float)h0);
        f16 l1 = (f16)(fv[2*j+1] - (float)h1);
        hw[j] = h_bits(h0) | ((u32)h_bits(h1) << 16);
        lw[j] = h_bits(l0) | ((u32)h_bits(l1) << 16);
    }
    H = (uint4){hw[0], hw[1], hw[2], hw[3]};
    L = (uint4){lw[0], lw[1], lw[2], lw[3]};
}

// ---------------------------------------------------------------------------
// Kernel 1: prep = W transpose/convert only (UNCHANGED).
// ---------------------------------------------------------------------------
__global__ __launch_bounds__(256) void prep_kernel(
    const float* __restrict__ Wq, const float* __restrict__ Wk,
    const float* __restrict__ Wv, u16* __restrict__ Wt)
{
    __shared__ float Wf[64][65];
    const int wb = blockIdx.x;          // 0..767
    const int c  = threadIdx.x;
    const int d0 = (wb & 15) * 64;
    const int h  = (wb >> 4) & 15;
    const int which = wb >> 8;
    const float* src = (which == 0) ? Wq : (which == 1) ? Wk : Wv;
    src += (size_t)h * D_ * DH_;

    #pragma unroll
    for (int it = 0; it < 4; ++it){
        int d  = (c >> 4) + 16 * it;
        int e4 = (c & 15) * 4;
        float4 v = *(const float4*)(src + (size_t)(d0 + d) * DH_ + e4);
        Wf[d][e4+0] = v.x; Wf[d][e4+1] = v.y; Wf[d][e4+2] = v.z; Wf[d][e4+3] = v.w;
    }
    __syncthreads();
    u16* dst = Wt + (size_t)(which * H_ + h) * DH_ * D_;
    #pragma unroll
    for (int it = 0; it < 4; ++it){
        int e  = (c >> 4) + 16 * it;
        int d4 = (c & 15) * 4;
        u16 q[4];
        #pragma unroll
        for (int j = 0; j < 4; ++j)
            q[j] = h_bits((f16)(Wf[d4 + j][e] * 64.0f));
        u32* p = (u32*)(dst + (size_t)e * D_ + d0 + d4);
        p[0] = q[0] | ((u32)q[1] << 16);
        p[1] = q[2] | ((u32)q[3] << 16);
    }
}

// ---------------------------------------------------------------------------
// Kernel 2 (R8): proj — same R0 structure + fused X split, but the MFMA
// shape switched 16x16x32 -> 32x32x16 (µbench 2075 -> 2495 TF, m119) and
// instruction count halved (16 mfma/k-step vs 32).  Per wave: 64x64 = 2x2
// supertiles of 32x32, acc[2][2] f32x16.  Fragment maps (HW-verified, §3):
//   A/B: m|n = lane&31, k = 8*(lane>>5)+j  (16 k per mfma, kh in {0,16})
//   C/D: col = lane&31, row = (reg&3)+8*(reg>>2)+4*(lane>>5)
// LDS traffic unchanged (12 x 16B reads/k-step); staging/split unchanged.
// ---------------------------------------------------------------------------
#define PKS 40

__global__ __launch_bounds__(256, 3) void proj_kernel(
    const float* __restrict__ X,
    const u16* __restrict__ Wt,
    const float* __restrict__ bq, const float* __restrict__ bk,
    const float* __restrict__ bv,
    f16* __restrict__ Qh, f16* __restrict__ Kh, f16* __restrict__ Vt)
{
    __shared__ u16 XsHi[128 * PKS], XsLo[128 * PKS], Bs[128 * PKS];

    const int tid  = threadIdx.x;
    const int lane = tid & 63;
    const int w    = tid >> 6;
    const int l31  = lane & 31;
    const int lhi  = lane >> 5;        // 0/1
    const int khb  = lhi * 8;          // k sub-offset within 16
    const int wr   = (w >> 1) * 64;
    const int wc   = (w & 1) * 64;
    const int m0   = blockIdx.x * 128;
    const int c0   = blockIdx.y * 128;

    const int sr  = tid >> 2;          // 0..63
    const int sch = (tid & 3) * 8;     // 0,8,16,24

    const float* x0 = X + (size_t)(m0 + sr) * D_ + sch;
    const float* x1 = x0 + (size_t)64 * D_;
    const u16*  wb0 = Wt + (size_t)(c0 + sr) * D_ + sch;
    const u16*  wb1 = wb0 + (size_t)64 * D_;

    // prologue: load tile0 raw + W, convert tile0
    float4 p00 = *(const float4*)x0, p01 = *(const float4*)(x0 + 4);
    float4 p10 = *(const float4*)x1, p11 = *(const float4*)(x1 + 4);
    uint4 rw0 = *(const uint4*)wb0, rw1 = *(const uint4*)wb1;
    uint4 h0, l0, h1, l1;
    split8(p00, p01, h0, l0);
    split8(p10, p11, h1, l1);

    f32x16 acc[2][2];
    #pragma unroll
    for (int i = 0; i < 2; ++i)
        #pragma unroll
        for (int j = 0; j < 2; ++j)
            #pragma unroll
            for (int r = 0; r < 16; ++r)
                acc[i][j][r] = 0.f;

    for (int k0 = 0; k0 < D_; k0 += 32){
        __syncthreads();
        *(uint4*)&XsHi[sr * PKS + sch]        = h0;
        *(uint4*)&XsHi[(sr + 64) * PKS + sch] = h1;
        *(uint4*)&XsLo[sr * PKS + sch]        = l0;
        *(uint4*)&XsLo[(sr + 64) * PKS + sch] = l1;
        *(uint4*)&Bs[sr * PKS + sch]          = rw0;
        *(uint4*)&Bs[(sr + 64) * PKS + sch]   = rw1;
        const int kn = k0 + 32;
        if (kn < D_){
            p00 = *(const float4*)(x0 + kn); p01 = *(const float4*)(x0 + kn + 4);
            p10 = *(const float4*)(x1 + kn); p11 = *(const float4*)(x1 + kn + 4);
            rw0 = *(const uint4*)(wb0 + kn); rw1 = *(const uint4*)(wb1 + kn);
        }
        __syncthreads();

        half8 ahi[2][2], alo[2][2], bf[2][2];   // [tile][kh]
        #pragma unroll
        for (int mt = 0; mt < 2; ++mt){
            int row = wr + 32 * mt + l31;
            #pragma unroll
            for (int kh = 0; kh < 2; ++kh){
                ahi[mt][kh] = __builtin_bit_cast(half8,
                    *(const uint4*)&XsHi[row * PKS + kh * 16 + khb]);
                alo[mt][kh] = __builtin_bit_cast(half8,
                    *(const uint4*)&XsLo[row * PKS + kh * 16 + khb]);
            }
        }
        #pragma unroll
        for (int nt = 0; nt < 2; ++nt){
            int row = wc + 32 * nt + l31;
            #pragma unroll
            for (int kh = 0; kh < 2; ++kh)
                bf[nt][kh] = __builtin_bit_cast(half8,
                    *(const uint4*)&Bs[row * PKS + kh * 16 + khb]);
        }
        #pragma unroll
        for (int mt = 0; mt < 2; ++mt)
            #pragma unroll
            for (int nt = 0; nt < 2; ++nt){
                acc[mt][nt] = __builtin_amdgcn_mfma_f32_32x32x16_f16(ahi[mt][0], bf[nt][0], acc[mt][nt], 0, 0, 0);
                acc[mt][nt] = __builtin_amdgcn_mfma_f32_32x32x16_f16(ahi[mt][1], bf[nt][1], acc[mt][nt], 0, 0, 0);
                acc[mt][nt] = __builtin_amdgcn_mfma_f32_32x32x16_f16(alo[mt][0], bf[nt][0], acc[mt][nt], 0, 0, 0);
                acc[mt][nt] = __builtin_amdgcn_mfma_f32_32x32x16_f16(alo[mt][1], bf[nt][1], acc[mt][nt], 0, 0, 0);
            }

        // convert tile k+1 AFTER the MFMA cluster (VALU co-issues with MFMA)
        if (kn < D_){
            split8(p00, p01, h0, l0);
            split8(p10, p11, h1, l1);
        }
    }

    const float QSCALE = 0.125f * 1.44269504088896340736f;
    const float INV64  = 0.015625f;
    #pragma unroll
    for (int nt = 0; nt < 2; ++nt){
        int colg  = c0 + wc + 32 * nt + l31;
        int which = colg >> 10;          // uniform across the wave per nt
        int h     = (colg >> 6) & 15;    // uniform across the wave per nt
        int e     = colg & 63;
        const float* bp = (which == 0) ? bq : (which == 1) ? bk : bv;
        float bias = bp[h * DH_ + e];
        if (which < 2){
            f16* op = (which == 0) ? Qh : Kh;
            float scale = (which == 0) ? QSCALE : 1.0f;
            #pragma unroll
            for (int mt = 0; mt < 2; ++mt)
                #pragma unroll
                for (int r = 0; r < 16; ++r){
                    int row = (r & 3) + 8 * (r >> 2) + 4 * lhi;
                    int sg  = m0 + wr + 32 * mt + row;
                    int b   = sg >> 11;
                    int s   = sg & (S_ - 1);
                    float val = (acc[mt][nt][r] * INV64 + bias) * scale;
                    op[((size_t)(b * H_ + h) * S_ + s) * DH_ + e] = (f16)val;
                }
        } else {
            // V transposed: reg groups of 4 (j=0..3) are t-consecutive
            #pragma unroll
            for (int mt = 0; mt < 2; ++mt)
                #pragma unroll
                for (int g = 0; g < 4; ++g){
                    int t0g = m0 + wr + 32 * mt + 8 * g + 4 * lhi;
                    int b   = t0g >> 11;
                    int s0  = t0g & (S_ - 1);
                    u16 p[4];
                    #pragma unroll
                    for (int j = 0; j < 4; ++j)
                        p[j] = h_bits((f16)(acc[mt][nt][4*g + j] * INV64 + bias));
                    uint2 pk;
                    pk.x = p[0] | ((u32)p[1] << 16);
                    pk.y = p[2] | ((u32)p[3] << 16);
                    *(uint2*)((u16*)Vt + ((size_t)((b * H_ + h) * DH_ + e)) * S_ + s0) = pk;
                }
        }
    }
}

// ---------------------------------------------------------------------------
// Kernel 3: attention — UNCHANGED from R7 (BK=128, neutral-to-slightly-
// better vs R0; proven structure).
// ---------------------------------------------------------------------------
#define AKS 72
#define VKS 136

__global__ __launch_bounds__(256, 4) void attn_kernel(
    const f16* __restrict__ Qh, const f16* __restrict__ Kh,
    const f16* __restrict__ Vt, float* __restrict__ Out)
{
    __shared__ u16 Ks[128 * AKS];   // K tile [t(128)][e(64)+pad]
    __shared__ u16 Vs[64 * VKS];    // V tile [e(64)][t(128)+pad]

    const int tid  = threadIdx.x;
    const int lane = tid & 63;
    const int w    = tid >> 6;
    const int quad = lane >> 4;
    const int ln   = lane & 15;
    const int hb   = blockIdx.x;            // b*H + h  (XCD = hb % 8)
    const int i    = blockIdx.y;            // pair index
    const int h    = hb & 15;
    const int b    = hb >> 4;
    const int bh   = hb;
    const int sub  = w & 1;
    const int qbase = (w >> 1) ? (S_ - 32 * (i + 1) + 16 * sub)
                               : (32 * i + 16 * sub);
    const int vmax  = S_ - 32 * i - 1;      // highest t any wave's PV needs

    const u16* Qg = (const u16*)Qh + (size_t)bh * S_ * DH_;
    const u16* Kg = (const u16*)Kh + (size_t)bh * S_ * DH_;
    const u16* Vg = (const u16*)Vt + (size_t)bh * DH_ * S_;

    // Q fragments straight from global (B-operand: n=q=ln, k=d=32ks+8quad+j)
    half8 qf[2];
    #pragma unroll
    for (int ks = 0; ks < 2; ++ks)
        qf[ks] = __builtin_bit_cast(half8,
            *(const uint4*)(Qg + (size_t)(qbase + ln) * DH_ + 32 * ks + 8 * quad));

    // staging coords: K rows kr+32j (j=0..3); V e-rows kr,kr+32 x col-halves
    const int kr = tid >> 3;           // 0..31
    const int kc = (tid & 7) * 8;      // 0..56

    // prefetch tile 0 (t in [0,128); 64 <= vmax always since vmax >= 1055)
    uint4 ka = *(const uint4*)(Kg + (size_t)(kr)      * DH_ + kc);
    uint4 kb = *(const uint4*)(Kg + (size_t)(kr + 32) * DH_ + kc);
    uint4 kcg= *(const uint4*)(Kg + (size_t)(kr + 64) * DH_ + kc);
    uint4 kd = *(const uint4*)(Kg + (size_t)(kr + 96) * DH_ + kc);
    uint4 va = *(const uint4*)(Vg + (size_t)(kr)      * S_ + kc);
    uint4 vb = *(const uint4*)(Vg + (size_t)(kr + 32) * S_ + kc);
    uint4 vc = *(const uint4*)(Vg + (size_t)(kr)      * S_ + 64 + kc);
    uint4 vd = *(const uint4*)(Vg + (size_t)(kr + 32) * S_ + 64 + kc);

    float l_r = 0.f;
    f32x4 o_acc[4];
    #pragma unroll
    for (int nt = 0; nt < 4; ++nt) o_acc[nt] = (f32x4){0.f, 0.f, 0.f, 0.f};

    const int qrow   = qbase + ln;     // this lane's q (n-dim)
    const int pv_lim = qbase + 15;     // wave-uniform PV bound

    for (int t0 = 0; t0 < S_; t0 += 128){
        __syncthreads();               // all waves done reading prev tile
        *(uint4*)&Ks[(kr)      * AKS + kc] = ka;
        *(uint4*)&Ks[(kr + 32) * AKS + kc] = kb;
        *(uint4*)&Ks[(kr + 64) * AKS + kc] = kcg;
        *(uint4*)&Ks[(kr + 96) * AKS + kc] = kd;
        if (t0 <= vmax){
            *(uint4*)&Vs[(kr)      * VKS + kc] = va;
            *(uint4*)&Vs[(kr + 32) * VKS + kc] = vb;
        }
        if (t0 + 64 <= vmax){
            *(uint4*)&Vs[(kr)      * VKS + 64 + kc] = vc;
            *(uint4*)&Vs[(kr + 32) * VKS + 64 + kc] = vd;
        }
        // prefetch tile t0+128 (hidden behind this tile's 2x compute)
        const int tp = t0 + 128;
        if (tp < S_){
            ka = *(const uint4*)(Kg + (size_t)(tp + kr)      * DH_ + kc);
            kb = *(const uint4*)(Kg + (size_t)(tp + kr + 32) * DH_ + kc);
            kcg= *(const uint4*)(Kg + (size_t)(tp + kr + 64) * DH_ + kc);
            kd = *(const uint4*)(Kg + (size_t)(tp + kr + 96) * DH_ + kc);
            if (tp <= vmax){
                va = *(const uint4*)(Vg + (size_t)(kr)      * S_ + tp + kc);
                vb = *(const uint4*)(Vg + (size_t)(kr + 32) * S_ + tp + kc);
            }
            if (tp + 64 <= vmax){
                vc = *(const uint4*)(Vg + (size_t)(kr)      * S_ + tp + 64 + kc);
                vd = *(const uint4*)(Vg + (size_t)(kr + 32) * S_ + tp + 64 + kc);
            }
        }
        __syncthreads();               // LDS tile ready

        // two 64-t sub-tiles, identical t-order to R0's successive iters
        #pragma unroll
        for (int si = 0; si < 2; ++si){
            const int tb   = t0 + 64 * si;
            const int koff = 64 * si * AKS;
            const int voff = 64 * si;

            f32x4 sc[4];
            #pragma unroll
            for (int mt = 0; mt < 4; ++mt) sc[mt] = (f32x4){0.f, 0.f, 0.f, 0.f};
            #pragma unroll
            for (int ks = 0; ks < 2; ++ks)
                #pragma unroll
                for (int mt = 0; mt < 4; ++mt){
                    half8 kf = __builtin_bit_cast(half8,
                        *(const uint4*)&Ks[koff + (16 * mt + ln) * AKS + 32 * ks + 8 * quad]);
                    sc[mt] = __builtin_amdgcn_mfma_f32_16x16x32_f16(kf, qf[ks], sc[mt], 0, 0, 0);
                }

            // p = exp2(s); denominator = plain running row-sum over ALL t
            #pragma unroll
            for (int mt = 0; mt < 4; ++mt)
                #pragma unroll
                for (int r = 0; r < 4; ++r)
                    sc[mt][r] = EXP2(sc[mt][r]);
            float s = ((sc[0][0] + sc[0][1] + sc[0][2] + sc[0][3]) +
                       (sc[1][0] + sc[1][1] + sc[1][2] + sc[1][3])) +
                      ((sc[2][0] + sc[2][1] + sc[2][2] + sc[2][3]) +
                       (sc[3][0] + sc[3][1] + sc[3][2] + sc[3][3]));
            s += __shfl_xor(s, 16);
            s += __shfl_xor(s, 32);
            l_r += s;

            // PV per 16-t subtile; only the subtile starting AT qbase partial
            #pragma unroll
            for (int mt = 0; mt < 4; ++mt){
                const int ts = tb + 16 * mt;
                if (ts <= pv_lim){         // wave-uniform
                    half4 pf;
                    if (ts == qbase){      // the one partial subtile
                        int tq = ts + 4 * quad;
                        #pragma unroll
                        for (int r = 0; r < 4; ++r)
                            pf[r] = (tq + r > qrow) ? (f16)0.f : (f16)sc[mt][r];
                    } else {               // fully below diagonal
                        #pragma unroll
                        for (int r = 0; r < 4; ++r)
                            pf[r] = (f16)sc[mt][r];
                    }
                    #pragma unroll
                    for (int nt = 0; nt < 4; ++nt){
                        half4 vf = __builtin_bit_cast(half4,
                            *(const uint2*)&Vs[(16 * nt + ln) * VKS + voff + 16 * mt + 4 * quad]);
                        o_acc[nt] = __builtin_amdgcn_mfma_f32_16x16x16f16(pf, vf, o_acc[nt], 0, 0, 0);
                    }
                }
            }
        }
    }

    // epilogue: o rows at q = qbase+4quad+r; l lives at lane ln=row
    #pragma unroll
    for (int r = 0; r < 4; ++r){
        float lv  = __shfl(l_r, (lane & 48) | (4 * quad + r));
        float inv = 1.0f / lv;
        int sg = qbase + 4 * quad + r;
        float* op = Out + ((size_t)b * S_ + sg) * D_ + h * DH_;
        #pragma unroll
        for (int nt = 0; nt < 4; ++nt)
            op[16 * nt + ln] = o_acc[nt][r] * inv;
    }
}

// ---------------------------------------------------------------------------
extern "C" void kernel_launch(void* const* d_in, const int* in_sizes, int n_in,
                              void* d_out, int out_size, void* d_ws, size_t ws_size,
                              hipStream_t stream)
{
    const float* X  = (const float*)d_in[0];
    const float* Wq = (const float*)d_in[1];
    const float* bq = (const float*)d_in[2];
    const float* Wk = (const float*)d_in[3];
    const float* bk = (const float*)d_in[4];
    const float* Wv = (const float*)d_in[5];
    const float* bv = (const float*)d_in[6];
    float* out = (float*)d_out;

    // workspace (~31.5 MiB): Wt | Qh | Kh | Vt
    u16* Wt  = (u16*)d_ws;                    // 3,145,728 u16
    f16* Qh  = (f16*)(Wt + 3145728);
    f16* Kh  = Qh + 4194304;
    f16* Vt  = Kh + 4194304;

    prep_kernel<<<dim3(768), 256, 0, stream>>>(Wq, Wk, Wv, Wt);
    proj_kernel<<<dim3(32, 24), 256, 0, stream>>>(X, Wt, bq, bk, bv, Qh, Kh, Vt);
    attn_kernel<<<dim3(32, 32), 256, 0, stream>>>(Qh, Kh, Vt, out);
}